// Round 3
// baseline (3048.086 us; speedup 1.0000x reference)
//
#include <hip/hip_runtime.h>
#include <math.h>

#define DIN 256

// ---------------- weight fusion ----------------
// Bf[r, c] = sum_t ibW_sub[i, t] * lnW[sub*dmid + t, c],  r = sub*256 + i
__global__ void fuse_w_kernel(const float* __restrict__ w0,
                              const float* __restrict__ w1,
                              const float* __restrict__ w2,
                              const float* __restrict__ lnW,
                              float* __restrict__ Bf, int dmid, int dn) {
  int idx = blockIdx.x * blockDim.x + threadIdx.x;
  int total = 768 * dn;
  if (idx >= total) return;
  int r = idx / dn, c = idx - r * dn;
  int sub = r >> 8, i = r & 255;
  const float* W = (sub == 0) ? w0 : (sub == 1) ? w1 : w2;
  float acc = 0.f;
  for (int t = 0; t < dmid; ++t)
    acc += W[i * dmid + t] * lnW[(sub * dmid + t) * dn + c];
  Bf[idx] = acc;
}

__global__ void fuse_b_kernel(const float* __restrict__ b0,
                              const float* __restrict__ b1,
                              const float* __restrict__ b2,
                              const float* __restrict__ lnW,
                              const float* __restrict__ lnb,
                              float* __restrict__ biasf, int dmid, int dn) {
  int c = blockIdx.x * blockDim.x + threadIdx.x;
  if (c >= dn) return;
  float acc = lnb[c];
  for (int t = 0; t < dmid; ++t) acc += b0[t] * lnW[(0 * dmid + t) * dn + c];
  for (int t = 0; t < dmid; ++t) acc += b1[t] * lnW[(1 * dmid + t) * dn + c];
  for (int t = 0; t < dmid; ++t) acc += b2[t] * lnW[(2 * dmid + t) * dn + c];
  biasf[c] = acc;
}

// ---------------- CSR build ----------------
__global__ void hist_kernel(const int* __restrict__ ei, int* cnt, int E) {
  int e = blockIdx.x * 256 + threadIdx.x;
  if (e < E) atomicAdd(&cnt[ei[E + e]], 1);
}

// single workgroup exclusive scan; cnt may alias cur
__global__ void scan_kernel(const int* cnt, int* offs, int* cur, int n) {
  __shared__ int buf[1024];
  __shared__ int running;
  if (threadIdx.x == 0) running = 0;
  __syncthreads();
  for (int base = 0; base < n; base += 1024) {
    int i = base + (int)threadIdx.x;
    int c = (i < n) ? cnt[i] : 0;
    buf[threadIdx.x] = c;
    __syncthreads();
    for (int off = 1; off < 1024; off <<= 1) {
      int v = (threadIdx.x >= (unsigned)off) ? buf[threadIdx.x - off] : 0;
      __syncthreads();
      buf[threadIdx.x] += v;
      __syncthreads();
    }
    int incl = buf[threadIdx.x];
    int r = running;
    if (i < n) { int ex = r + incl - c; offs[i] = ex; cur[i] = ex; }
    __syncthreads();
    if (threadIdx.x == 1023) running = r + incl;
    __syncthreads();
  }
  if (threadIdx.x == 0) offs[n] = running;
}

__global__ void fill_kernel(const int* __restrict__ ei, const float* __restrict__ ew,
                            int* cur, int* __restrict__ csr_src,
                            float* __restrict__ csr_w, int E) {
  int e = blockIdx.x * 256 + threadIdx.x;
  if (e >= E) return;
  int dst = ei[E + e];
  int pos = atomicAdd(&cur[dst], 1);
  csr_src[pos] = ei[e];
  csr_w[pos] = ew[e];
}

// ---------------- aggregation: one wave per dst row ----------------
__global__ __launch_bounds__(256)
void agg_kernel(const int* __restrict__ offs, const int* __restrict__ csr_src,
                const float* __restrict__ csr_w, const float* __restrict__ X,
                float* __restrict__ Z, int Nn) {
  int wid = blockIdx.x * 4 + (threadIdx.x >> 6);
  if (wid >= Nn) return;
  int lane = threadIdx.x & 63;
  int beg = offs[wid], end = offs[wid + 1];
  float4 acc = make_float4(0.f, 0.f, 0.f, 0.f);
  for (int i = beg; i < end; ++i) {
    int s = csr_src[i];
    float w = csr_w[i];
    float4 v = *(const float4*)(X + (size_t)s * DIN + lane * 4);
    acc.x = fmaf(w, v.x, acc.x);
    acc.y = fmaf(w, v.y, acc.y);
    acc.z = fmaf(w, v.z, acc.z);
    acc.w = fmaf(w, v.w, acc.w);
  }
  *(float4*)(Z + (size_t)wid * DIN + lane * 4) = acc;
}

// ---------------- fused-K GEMM: C = [A0|A1|A2] @ B + bias ----------------
#define BM 64
#define BN 64
#define BK 32
__global__ __launch_bounds__(256)
void gemm3_kernel(const float* __restrict__ A0, const float* __restrict__ A1,
                  const float* __restrict__ A2, const float* __restrict__ B,
                  const float* __restrict__ bias, float* __restrict__ C,
                  int M, int dn) {
  __shared__ float As[BK][BM + 4];   // stride 68 floats = 272 B (16B aligned)
  __shared__ float Bs[BK][BN];
  int tid = threadIdx.x;
  int tx = tid & 15, ty = tid >> 4;
  int m0 = blockIdx.y * BM, n0 = blockIdx.x * BN;
  float acc[4][4] = {};
  const float* Achunk[3] = {A0, A1, A2};
  int af = tid & 7;   // float4 index along k
  int am = tid >> 3;  // row 0..31 (and +32)
  int bf = tid & 15;  // float4 index along n
  int bk = tid >> 4;  // k row 0..15 (and +16)

  for (int k0 = 0; k0 < 768; k0 += BK) {
    const float* A = Achunk[k0 >> 8];
    int kloc = k0 & 255;
#pragma unroll
    for (int h = 0; h < 2; ++h) {
      int row = m0 + am + h * 32;
      float4 v = make_float4(0.f, 0.f, 0.f, 0.f);
      if (row < M) v = *(const float4*)(A + (size_t)row * DIN + kloc + af * 4);
      As[af * 4 + 0][am + h * 32] = v.x;
      As[af * 4 + 1][am + h * 32] = v.y;
      As[af * 4 + 2][am + h * 32] = v.z;
      As[af * 4 + 3][am + h * 32] = v.w;
    }
#pragma unroll
    for (int h = 0; h < 2; ++h) {
      int kk = bk + h * 16;
      *(float4*)(&Bs[kk][bf * 4]) =
          *(const float4*)(B + (size_t)(k0 + kk) * dn + n0 + bf * 4);
    }
    __syncthreads();
#pragma unroll
    for (int kk = 0; kk < BK; ++kk) {
      float4 a = *(const float4*)(&As[kk][ty * 4]);
      float4 b = *(const float4*)(&Bs[kk][tx * 4]);
      float av[4] = {a.x, a.y, a.z, a.w};
      float bv[4] = {b.x, b.y, b.z, b.w};
#pragma unroll
      for (int i = 0; i < 4; ++i)
#pragma unroll
        for (int j = 0; j < 4; ++j)
          acc[i][j] = fmaf(av[i], bv[j], acc[i][j]);
    }
    __syncthreads();
  }
#pragma unroll
  for (int i = 0; i < 4; ++i) {
    int row = m0 + ty * 4 + i;
    if (row >= M) continue;
#pragma unroll
    for (int j = 0; j < 4; ++j) {
      int col = n0 + tx * 4 + j;
      C[(size_t)row * dn + col] = acc[i][j] + bias[col];
    }
  }
}

// ---------------- log_softmax over rows of 64 ----------------
__global__ __launch_bounds__(256)
void logsoftmax_kernel(float* __restrict__ out, int Nn) {
  int row = blockIdx.x * 4 + (threadIdx.x >> 6);
  if (row >= Nn) return;
  int lane = threadIdx.x & 63;
  float v = out[(size_t)row * 64 + lane];
  float m = v;
  for (int off = 32; off; off >>= 1) m = fmaxf(m, __shfl_xor(m, off));
  float ex = expf(v - m);
  float s = ex;
  for (int off = 32; off; off >>= 1) s += __shfl_xor(s, off);
  out[(size_t)row * 64 + lane] = v - m - logf(s);
}

extern "C" void kernel_launch(void* const* d_in, const int* in_sizes, int n_in,
                              void* d_out, int out_size, void* d_ws, size_t ws_size,
                              hipStream_t stream) {
  const float* x  = (const float*)d_in[0];
  const int* ei1  = (const int*)d_in[1];
  const float* ew1 = (const float*)d_in[2];
  const int* ei2  = (const int*)d_in[3];
  const float* ew2 = (const float*)d_in[4];
  int Nn = in_sizes[0] / 256;
  int E  = in_sizes[1] / 2;

  const float* ibW[3][3]; const float* ibB[3][3];
  int p = 5;
  for (int b = 0; b < 3; ++b)
    for (int q = 0; q < 3; ++q) {
      ibW[b][q] = (const float*)d_in[p++];
      ibB[b][q] = (const float*)d_in[p++];
    }
  const float* lnW[3] = {(const float*)d_in[23], (const float*)d_in[25], (const float*)d_in[27]};
  const float* lnb[3] = {(const float*)d_in[24], (const float*)d_in[26], (const float*)d_in[28]};
  int dmid[3] = {256, 256, 64}, dn[3] = {256, 256, 64};

  char* ws = (char*)d_ws;
  size_t off = 0;
  auto alloc = [&](size_t bytes) {
    void* pp = ws + off;
    off = (off + bytes + 255) & ~(size_t)255;
    return pp;
  };
  float* X1 = (float*)alloc((size_t)Nn * 256 * 4);
  float* X2 = (float*)alloc((size_t)Nn * 256 * 4);
  float* z1 = (float*)alloc((size_t)Nn * 256 * 4);
  float* z2 = (float*)alloc((size_t)Nn * 256 * 4);
  float* Bf[3]; float* biasf[3];
  for (int b = 0; b < 3; ++b) {
    Bf[b]    = (float*)alloc((size_t)768 * dn[b] * 4);
    biasf[b] = (float*)alloc((size_t)dn[b] * 4);
  }
  int* offs[2]; int* cur[2]; int* csrc[2]; float* cw[2];
  const int* eis[2] = {ei1, ei2};
  const float* ews[2] = {ew1, ew2};
  for (int g = 0; g < 2; ++g) {
    offs[g] = (int*)alloc((size_t)(Nn + 1) * 4);
    cur[g]  = (int*)alloc((size_t)Nn * 4);
    csrc[g] = (int*)alloc((size_t)E * 4);
    cw[g]   = (float*)alloc((size_t)E * 4);
  }

  // weight fusion
  for (int b = 0; b < 3; ++b) {
    int total = 768 * dn[b];
    fuse_w_kernel<<<(total + 255) / 256, 256, 0, stream>>>(
        ibW[b][0], ibW[b][1], ibW[b][2], lnW[b], Bf[b], dmid[b], dn[b]);
    fuse_b_kernel<<<1, 256, 0, stream>>>(
        ibB[b][0], ibB[b][1], ibB[b][2], lnW[b], lnb[b], biasf[b], dmid[b], dn[b]);
  }

  // CSR build (per graph, reused by all 3 blocks)
  for (int g = 0; g < 2; ++g) {
    hipMemsetAsync(cur[g], 0, (size_t)Nn * 4, stream);
    hist_kernel<<<(E + 255) / 256, 256, 0, stream>>>(eis[g], cur[g], E);
    scan_kernel<<<1, 1024, 0, stream>>>(cur[g], offs[g], cur[g], Nn);
    fill_kernel<<<(E + 255) / 256, 256, 0, stream>>>(eis[g], ews[g], cur[g], csrc[g], cw[g], E);
  }

  // 3 blocks
  const float* Xin = x;
  float* Xout[3] = {X1, X2, (float*)d_out};
  int aggGrid = (Nn + 3) / 4;
  for (int b = 0; b < 3; ++b) {
    agg_kernel<<<aggGrid, 256, 0, stream>>>(offs[0], csrc[0], cw[0], Xin, z1, Nn);
    agg_kernel<<<aggGrid, 256, 0, stream>>>(offs[1], csrc[1], cw[1], Xin, z2, Nn);
    dim3 grid(dn[b] / 64, (Nn + 63) / 64);
    gemm3_kernel<<<grid, 256, 0, stream>>>(Xin, z1, z2, Bf[b], biasf[b], Xout[b], Nn, dn[b]);
    Xin = Xout[b];
  }
  logsoftmax_kernel<<<aggGrid, 256, 0, stream>>>((float*)d_out, Nn);
}

// Round 6
// 2530.879 us; speedup vs baseline: 1.2044x; 1.2044x over previous
//
#include <hip/hip_runtime.h>
#include <math.h>

typedef __attribute__((ext_vector_type(8))) short bf16x8;
typedef __attribute__((ext_vector_type(4))) float f32x4;

__device__ inline ushort f2bf(float f) {
  unsigned u = __builtin_bit_cast(unsigned, f);
  unsigned r = (u + 0x7FFFu + ((u >> 16) & 1u)) >> 16;
  return (ushort)r;
}
__device__ inline float bf2f(ushort h) {
  return __builtin_bit_cast(float, (unsigned)h << 16);
}
__device__ inline void split2(float f, ushort& hi, ushort& lo) {
  hi = f2bf(f);
  lo = f2bf(f - bf2f(hi));
}

// ---------------- weight fusion: BT[c][r] = sum_t W_sub[i,t]*lnW[sub*dmid+t,c], r=sub*256+i
__global__ void fuse_w_kernel(const float* __restrict__ w0,
                              const float* __restrict__ w1,
                              const float* __restrict__ w2,
                              const float* __restrict__ lnW,
                              ushort* __restrict__ BTh, ushort* __restrict__ BTl,
                              int dmid, int dn) {
  int idx = blockIdx.x * blockDim.x + threadIdx.x;
  int total = 768 * dn;
  if (idx >= total) return;
  int r = idx / dn, c = idx - r * dn;
  int sub = r >> 8, i = r & 255;
  const float* W = (sub == 0) ? w0 : (sub == 1) ? w1 : w2;
  float acc = 0.f;
  for (int t = 0; t < dmid; ++t)
    acc += W[i * dmid + t] * lnW[(sub * dmid + t) * dn + c];
  ushort hi, lo; split2(acc, hi, lo);
  BTh[(size_t)c * 768 + r] = hi;
  BTl[(size_t)c * 768 + r] = lo;
}

__global__ void fuse_b_kernel(const float* __restrict__ b0,
                              const float* __restrict__ b1,
                              const float* __restrict__ b2,
                              const float* __restrict__ lnW,
                              const float* __restrict__ lnb,
                              float* __restrict__ biasf, int dmid, int dn) {
  int c = blockIdx.x * blockDim.x + threadIdx.x;
  if (c >= dn) return;
  float acc = lnb[c];
  for (int t = 0; t < dmid; ++t) acc += b0[t] * lnW[(0 * dmid + t) * dn + c];
  for (int t = 0; t < dmid; ++t) acc += b1[t] * lnW[(1 * dmid + t) * dn + c];
  for (int t = 0; t < dmid; ++t) acc += b2[t] * lnW[(2 * dmid + t) * dn + c];
  biasf[c] = acc;
}

// ---------------- CSR build ----------------
__global__ void hist_kernel(const int* __restrict__ ei, int* cnt, int E) {
  int e = blockIdx.x * 256 + threadIdx.x;
  if (e < E) atomicAdd(&cnt[ei[E + e]], 1);
}

__global__ void scan_kernel(const int* cnt, int* offs, int* cur, int n) {
  __shared__ int buf[1024];
  __shared__ int running;
  if (threadIdx.x == 0) running = 0;
  __syncthreads();
  for (int base = 0; base < n; base += 1024) {
    int i = base + (int)threadIdx.x;
    int c = (i < n) ? cnt[i] : 0;
    buf[threadIdx.x] = c;
    __syncthreads();
    for (int off = 1; off < 1024; off <<= 1) {
      int v = (threadIdx.x >= (unsigned)off) ? buf[threadIdx.x - off] : 0;
      __syncthreads();
      buf[threadIdx.x] += v;
      __syncthreads();
    }
    int incl = buf[threadIdx.x];
    int r = running;
    if (i < n) { int ex = r + incl - c; offs[i] = ex; cur[i] = ex; }
    __syncthreads();
    if (threadIdx.x == 1023) running = r + incl;
    __syncthreads();
  }
  if (threadIdx.x == 0) offs[n] = running;
}

__global__ void fill_kernel(const int* __restrict__ ei, const float* __restrict__ ew,
                            int* cur, int2* __restrict__ csr, int E) {
  int e = blockIdx.x * 256 + threadIdx.x;
  if (e >= E) return;
  int dst = ei[E + e];
  int pos = atomicAdd(&cur[dst], 1);
  csr[pos] = make_int2(ei[e], __float_as_int(ew[e]));
}

// ---------------- x -> (hi,lo) bf16 split ----------------
__global__ void conv_split_kernel(const float* __restrict__ X,
                                  ushort* __restrict__ Xh, ushort* __restrict__ Xl,
                                  size_t n4) {
  size_t i = (size_t)blockIdx.x * 256 + threadIdx.x;
  if (i >= n4) return;
  float4 v = *(const float4*)(X + i * 4);
  ushort4 h, l;
  split2(v.x, h.x, l.x); split2(v.y, h.y, l.y);
  split2(v.z, h.z, l.z); split2(v.w, h.w, l.w);
  *(ushort4*)(Xh + i * 4) = h;
  *(ushort4*)(Xl + i * 4) = l;
}

// ---------------- aggregation: one wave per dst row, bf16 gather ----------------
__global__ __launch_bounds__(256)
void agg_bf16_kernel(const int* __restrict__ offs, const int2* __restrict__ csr,
                     const ushort* __restrict__ Xh,
                     ushort* __restrict__ Zh, ushort* __restrict__ Zl, int Nn) {
  int wid = blockIdx.x * 4 + (threadIdx.x >> 6);
  if (wid >= Nn) return;
  int lane = threadIdx.x & 63;
  int beg = offs[wid], end = offs[wid + 1];
  float a0 = 0.f, a1 = 0.f, a2 = 0.f, a3 = 0.f;
  for (int i = beg; i < end; ++i) {
    int2 p = csr[i];
    float w = __int_as_float(p.y);
    ushort4 v = *(const ushort4*)(Xh + (size_t)p.x * 256 + lane * 4);
    a0 = fmaf(w, bf2f(v.x), a0);
    a1 = fmaf(w, bf2f(v.y), a1);
    a2 = fmaf(w, bf2f(v.z), a2);
    a3 = fmaf(w, bf2f(v.w), a3);
  }
  ushort4 h, l;
  split2(a0, h.x, l.x); split2(a1, h.y, l.y);
  split2(a2, h.z, l.z); split2(a3, h.w, l.w);
  *(ushort4*)(Zh + (size_t)wid * 256 + lane * 4) = h;
  *(ushort4*)(Zl + (size_t)wid * 256 + lane * 4) = l;
}

// ---------------- MFMA GEMM: C = [A0|A1|A2](hi+lo) @ BT(hi+lo) + bias ----------------
// wave tile 64x64 via 4x4 frags of mfma_f32_16x16x32_bf16; 3-product hi/lo split.
// No LDS: B is L2-resident (786 KB), A streamed; frag loads form 16x64B segments.
template<int WM, int WN, bool OUTF32>
__global__ __launch_bounds__(256)
void gemm_mfma_kernel(const ushort* __restrict__ A0h, const ushort* __restrict__ A0l,
                      const ushort* __restrict__ A1h, const ushort* __restrict__ A1l,
                      const ushort* __restrict__ A2h, const ushort* __restrict__ A2l,
                      const ushort* __restrict__ BTh, const ushort* __restrict__ BTl,
                      const float* __restrict__ bias,
                      float* __restrict__ Cf, ushort* __restrict__ Chi,
                      ushort* __restrict__ Clo, int M, int dn) {
  int tid = threadIdx.x;
  int w = tid >> 6, lane = tid & 63;
  int wr = w / WN, wc = w % WN;
  int m0 = blockIdx.x * (WM * 64) + wr * 64;
  int n0 = wc * 64;
  int r16 = lane & 15, kg = lane >> 4;
  const ushort* Ah[3] = {A0h, A1h, A2h};
  const ushort* Al[3] = {A0l, A1l, A2l};
  f32x4 acc[4][4] = {};
  const bf16x8 zf = {0, 0, 0, 0, 0, 0, 0, 0};

  for (int k0 = 0; k0 < 768; k0 += 32) {
    const ushort* ah = Ah[k0 >> 8];
    const ushort* al = Al[k0 >> 8];
    int kl = (k0 & 255) + kg * 8;
    bf16x8 afh[4], afl[4], bfh[4], bfl[4];
#pragma unroll
    for (int i = 0; i < 4; ++i) {
      int row = m0 + i * 16 + r16;
      if (row < M) {
        afh[i] = *(const bf16x8*)(ah + (size_t)row * 256 + kl);
        afl[i] = *(const bf16x8*)(al + (size_t)row * 256 + kl);
      } else { afh[i] = zf; afl[i] = zf; }
    }
#pragma unroll
    for (int j = 0; j < 4; ++j) {
      int n = n0 + j * 16 + r16;
      bfh[j] = *(const bf16x8*)(BTh + (size_t)n * 768 + k0 + kg * 8);
      bfl[j] = *(const bf16x8*)(BTl + (size_t)n * 768 + k0 + kg * 8);
    }
#pragma unroll
    for (int i = 0; i < 4; ++i)
#pragma unroll
      for (int j = 0; j < 4; ++j) {
        acc[i][j] = __builtin_amdgcn_mfma_f32_16x16x32_bf16(afh[i], bfh[j], acc[i][j], 0, 0, 0);
        acc[i][j] = __builtin_amdgcn_mfma_f32_16x16x32_bf16(afh[i], bfl[j], acc[i][j], 0, 0, 0);
        acc[i][j] = __builtin_amdgcn_mfma_f32_16x16x32_bf16(afl[i], bfh[j], acc[i][j], 0, 0, 0);
      }
  }
  // epilogue: C/D layout col=lane&15, row=(lane>>4)*4+reg (m89-verified)
  int qbase = (lane >> 4) * 4;
  int ccol = lane & 15;
#pragma unroll
  for (int i = 0; i < 4; ++i) {
#pragma unroll
    for (int j = 0; j < 4; ++j) {
      int col = n0 + j * 16 + ccol;
      float bv = bias[col];
#pragma unroll
      for (int q = 0; q < 4; ++q) {
        int row = m0 + i * 16 + qbase + q;
        if (row < M) {
          float c = acc[i][j][q] + bv;
          if (OUTF32) {
            Cf[(size_t)row * dn + col] = c;
          } else {
            ushort hi, lo; split2(c, hi, lo);
            Chi[(size_t)row * dn + col] = hi;
            Clo[(size_t)row * dn + col] = lo;
          }
        }
      }
    }
  }
}

// ---------------- log_softmax over rows of 64 ----------------
__global__ __launch_bounds__(256)
void logsoftmax_kernel(float* __restrict__ out, int Nn) {
  int row = blockIdx.x * 4 + (threadIdx.x >> 6);
  if (row >= Nn) return;
  int lane = threadIdx.x & 63;
  float v = out[(size_t)row * 64 + lane];
  float m = v;
  for (int off = 32; off; off >>= 1) m = fmaxf(m, __shfl_xor(m, off));
  float ex = expf(v - m);
  float s = ex;
  for (int off = 32; off; off >>= 1) s += __shfl_xor(s, off);
  out[(size_t)row * 64 + lane] = v - m - logf(s);
}

extern "C" void kernel_launch(void* const* d_in, const int* in_sizes, int n_in,
                              void* d_out, int out_size, void* d_ws, size_t ws_size,
                              hipStream_t stream) {
  const float* x   = (const float*)d_in[0];
  const int* ei1   = (const int*)d_in[1];
  const float* ew1 = (const float*)d_in[2];
  const int* ei2   = (const int*)d_in[3];
  const float* ew2 = (const float*)d_in[4];
  int Nn = in_sizes[0] / 256;
  int E  = in_sizes[1] / 2;

  const float* ibW[3][3]; const float* ibB[3][3];
  int p = 5;
  for (int b = 0; b < 3; ++b)
    for (int q = 0; q < 3; ++q) {
      ibW[b][q] = (const float*)d_in[p++];
      ibB[b][q] = (const float*)d_in[p++];
    }
  const float* lnW[3] = {(const float*)d_in[23], (const float*)d_in[25], (const float*)d_in[27]};
  const float* lnb[3] = {(const float*)d_in[24], (const float*)d_in[26], (const float*)d_in[28]};
  int dmid[3] = {256, 256, 64}, dn[3] = {256, 256, 64};

  char* ws = (char*)d_ws;
  size_t off = 0;
  auto alloc = [&](size_t bytes) {
    void* pp = ws + off;
    off = (off + bytes + 255) & ~(size_t)255;
    return pp;
  };
  size_t act = (size_t)Nn * 256 * 2;  // one bf16 activation plane
  ushort* XAh = (ushort*)alloc(act); ushort* XAl = (ushort*)alloc(act);
  ushort* XBh = (ushort*)alloc(act); ushort* XBl = (ushort*)alloc(act);
  ushort* z1h = (ushort*)alloc(act); ushort* z1l = (ushort*)alloc(act);
  ushort* z2h = (ushort*)alloc(act); ushort* z2l = (ushort*)alloc(act);
  ushort* BTh[3]; ushort* BTl[3]; float* biasf[3];
  for (int b = 0; b < 3; ++b) {
    BTh[b]   = (ushort*)alloc((size_t)768 * dn[b] * 2);
    BTl[b]   = (ushort*)alloc((size_t)768 * dn[b] * 2);
    biasf[b] = (float*)alloc((size_t)dn[b] * 4);
  }
  int* offs[2]; int* cur[2]; int2* csr[2];
  const int* eis[2] = {ei1, ei2};
  const float* ews[2] = {ew1, ew2};
  for (int g = 0; g < 2; ++g) {
    offs[g] = (int*)alloc((size_t)(Nn + 1) * 4);
    cur[g]  = (int*)alloc((size_t)Nn * 4);
    csr[g]  = (int2*)alloc((size_t)E * 8);
  }

  // weight fusion (split bf16, transposed [dn][768])
  for (int b = 0; b < 3; ++b) {
    int total = 768 * dn[b];
    fuse_w_kernel<<<(total + 255) / 256, 256, 0, stream>>>(
        ibW[b][0], ibW[b][1], ibW[b][2], lnW[b], BTh[b], BTl[b], dmid[b], dn[b]);
    fuse_b_kernel<<<1, 256, 0, stream>>>(
        ibB[b][0], ibB[b][1], ibB[b][2], lnW[b], lnb[b], biasf[b], dmid[b], dn[b]);
  }

  // CSR build (per graph, reused by all 3 blocks)
  for (int g = 0; g < 2; ++g) {
    hipMemsetAsync(cur[g], 0, (size_t)Nn * 4, stream);
    hist_kernel<<<(E + 255) / 256, 256, 0, stream>>>(eis[g], cur[g], E);
    scan_kernel<<<1, 1024, 0, stream>>>(cur[g], offs[g], cur[g], Nn);
    fill_kernel<<<(E + 255) / 256, 256, 0, stream>>>(eis[g], ews[g], cur[g], csr[g], E);
  }

  // x -> bf16 hi/lo
  size_t n4 = (size_t)Nn * 64;  // float4 count
  conv_split_kernel<<<(int)((n4 + 255) / 256), 256, 0, stream>>>(x, XAh, XAl, n4);

  int aggGrid = (Nn + 3) / 4;
  int g1 = (Nn + 63) / 64;    // gemm grid, blocks 1-2 (BM=64)
  int g3 = (Nn + 255) / 256;  // gemm grid, block 3 (BM=256)

  // block 1: in XA(x) -> out XB
  agg_bf16_kernel<<<aggGrid, 256, 0, stream>>>(offs[0], csr[0], XAh, z1h, z1l, Nn);
  agg_bf16_kernel<<<aggGrid, 256, 0, stream>>>(offs[1], csr[1], XAh, z2h, z2l, Nn);
  gemm_mfma_kernel<1, 4, false><<<g1, 256, 0, stream>>>(
      XAh, XAl, z1h, z1l, z2h, z2l, BTh[0], BTl[0], biasf[0],
      nullptr, XBh, XBl, Nn, 256);

  // block 2: in XB -> out XA
  agg_bf16_kernel<<<aggGrid, 256, 0, stream>>>(offs[0], csr[0], XBh, z1h, z1l, Nn);
  agg_bf16_kernel<<<aggGrid, 256, 0, stream>>>(offs[1], csr[1], XBh, z2h, z2l, Nn);
  gemm_mfma_kernel<1, 4, false><<<g1, 256, 0, stream>>>(
      XBh, XBl, z1h, z1l, z2h, z2l, BTh[1], BTl[1], biasf[1],
      nullptr, XAh, XAl, Nn, 256);

  // block 3: in XA -> out d_out (fp32)
  agg_bf16_kernel<<<aggGrid, 256, 0, stream>>>(offs[0], csr[0], XAh, z1h, z1l, Nn);
  agg_bf16_kernel<<<aggGrid, 256, 0, stream>>>(offs[1], csr[1], XAh, z2h, z2l, Nn);
  gemm_mfma_kernel<4, 1, true><<<g3, 256, 0, stream>>>(
      XAh, XAl, z1h, z1l, z2h, z2l, BTh[2], BTl[2], biasf[2],
      (float*)d_out, nullptr, nullptr, Nn, 64);

  logsoftmax_kernel<<<aggGrid, 256, 0, stream>>>((float*)d_out, Nn);
}

// Round 9
// 2254.228 us; speedup vs baseline: 1.3522x; 1.1227x over previous
//
#include <hip/hip_runtime.h>
#include <math.h>

typedef __attribute__((ext_vector_type(8))) short bf16x8;
typedef __attribute__((ext_vector_type(4))) float f32x4;

__device__ inline ushort f2bf(float f) {
  unsigned u = __builtin_bit_cast(unsigned, f);
  unsigned r = (u + 0x7FFFu + ((u >> 16) & 1u)) >> 16;
  return (ushort)r;
}
__device__ inline float bf2f(ushort h) {
  return __builtin_bit_cast(float, (unsigned)h << 16);
}
__device__ inline void split2(float f, ushort& hi, ushort& lo) {
  hi = f2bf(f);
  lo = f2bf(f - bf2f(hi));
}

// ---------------- weight fusion: BT[c][r] = sum_t W_sub[i,t]*lnW[sub*dmid+t,c], r=sub*256+i
__global__ void fuse_w_kernel(const float* __restrict__ w0,
                              const float* __restrict__ w1,
                              const float* __restrict__ w2,
                              const float* __restrict__ lnW,
                              ushort* __restrict__ BTh, ushort* __restrict__ BTl,
                              int dmid, int dn) {
  int idx = blockIdx.x * blockDim.x + threadIdx.x;
  int total = 768 * dn;
  if (idx >= total) return;
  int r = idx / dn, c = idx - r * dn;
  int sub = r >> 8, i = r & 255;
  const float* W = (sub == 0) ? w0 : (sub == 1) ? w1 : w2;
  float acc = 0.f;
  for (int t = 0; t < dmid; ++t)
    acc += W[i * dmid + t] * lnW[(sub * dmid + t) * dn + c];
  ushort hi, lo; split2(acc, hi, lo);
  BTh[(size_t)c * 768 + r] = hi;
  BTl[(size_t)c * 768 + r] = lo;
}

// grid = dn blocks; 256 threads reduce 3*dmid terms for column c = blockIdx.x
__global__ __launch_bounds__(256)
void fuse_b_kernel(const float* __restrict__ b0,
                   const float* __restrict__ b1,
                   const float* __restrict__ b2,
                   const float* __restrict__ lnW,
                   const float* __restrict__ lnb,
                   float* __restrict__ biasf, int dmid, int dn) {
  int c = blockIdx.x;
  int t = threadIdx.x;
  float acc = 0.f;
  for (int k = t; k < 3 * dmid; k += 256) {
    int sub = k / dmid, w = k - sub * dmid;
    const float* bb = (sub == 0) ? b0 : (sub == 1) ? b1 : b2;
    acc += bb[w] * lnW[(size_t)k * dn + c];
  }
  for (int off = 32; off; off >>= 1) acc += __shfl_xor(acc, off);
  __shared__ float wsum[4];
  if ((t & 63) == 0) wsum[t >> 6] = acc;
  __syncthreads();
  if (t == 0) biasf[c] = lnb[c] + wsum[0] + wsum[1] + wsum[2] + wsum[3];
}

// ---------------- CSR build ----------------
__global__ void hist_kernel(const int* __restrict__ ei, int* cnt, int E) {
  int e = blockIdx.x * 256 + threadIdx.x;
  if (e < E) atomicAdd(&cnt[ei[E + e]], 1);
}

// single workgroup exclusive scan, wave-shuffle based (3 barriers/chunk)
__global__ void scan_kernel(const int* cnt, int* offs, int* cur, int n) {
  __shared__ int wsum[16];
  __shared__ int running;
  int t = threadIdx.x;
  if (t == 0) running = 0;
  __syncthreads();
  for (int base = 0; base < n; base += 1024) {
    int i = base + t;
    int c = (i < n) ? cnt[i] : 0;
    int v = c;
#pragma unroll
    for (int off = 1; off < 64; off <<= 1) {
      int u = __shfl_up(v, off);
      if ((t & 63) >= off) v += u;
    }
    if ((t & 63) == 63) wsum[t >> 6] = v;
    __syncthreads();
    if (t < 16) {
      int s = wsum[t];
#pragma unroll
      for (int off = 1; off < 16; off <<= 1) {
        int u = __shfl_up(s, off, 16);
        if (t >= off) s += u;
      }
      wsum[t] = s;
    }
    __syncthreads();
    int wid6 = t >> 6;
    int waveoff = (wid6 == 0) ? 0 : wsum[wid6 - 1];
    int incl = v + waveoff;
    int r = running;
    if (i < n) { int ex = r + incl - c; offs[i] = ex; cur[i] = ex; }
    __syncthreads();
    if (t == 1023) running = r + incl;
    __syncthreads();
  }
  if (t == 0) offs[n] = running;
}

__global__ void fill_kernel(const int* __restrict__ ei, const float* __restrict__ ew,
                            int* cur, int2* __restrict__ csr, int E) {
  int e = blockIdx.x * 256 + threadIdx.x;
  if (e >= E) return;
  int dst = ei[E + e];
  int pos = atomicAdd(&cur[dst], 1);
  csr[pos] = make_int2(ei[e], __float_as_int(ew[e]));
}

// ---------------- x -> (hi,lo) bf16 split ----------------
__global__ void conv_split_kernel(const float* __restrict__ X,
                                  ushort* __restrict__ Xh, ushort* __restrict__ Xl,
                                  size_t n4) {
  size_t i = (size_t)blockIdx.x * 256 + threadIdx.x;
  if (i >= n4) return;
  float4 v = *(const float4*)(X + i * 4);
  ushort4 h, l;
  split2(v.x, h.x, l.x); split2(v.y, h.y, l.y);
  split2(v.z, h.z, l.z); split2(v.w, h.w, l.w);
  *(ushort4*)(Xh + i * 4) = h;
  *(ushort4*)(Xl + i * 4) = l;
}

// ---------------- aggregation: one wave per dst row, bf16 gather ----------------
__global__ __launch_bounds__(256)
void agg_bf16_kernel(const int* __restrict__ offs, const int2* __restrict__ csr,
                     const ushort* __restrict__ Xh,
                     ushort* __restrict__ Zh, ushort* __restrict__ Zl, int Nn) {
  int wid = blockIdx.x * 4 + (threadIdx.x >> 6);
  if (wid >= Nn) return;
  int lane = threadIdx.x & 63;
  int beg = offs[wid], end = offs[wid + 1];
  float a0 = 0.f, a1 = 0.f, a2 = 0.f, a3 = 0.f;
  for (int i = beg; i < end; ++i) {
    int2 p = csr[i];
    float w = __int_as_float(p.y);
    ushort4 v = *(const ushort4*)(Xh + (size_t)p.x * 256 + lane * 4);
    a0 = fmaf(w, bf2f(v.x), a0);
    a1 = fmaf(w, bf2f(v.y), a1);
    a2 = fmaf(w, bf2f(v.z), a2);
    a3 = fmaf(w, bf2f(v.w), a3);
  }
  ushort4 h, l;
  split2(a0, h.x, l.x); split2(a1, h.y, l.y);
  split2(a2, h.z, l.z); split2(a3, h.w, l.w);
  *(ushort4*)(Zh + (size_t)wid * 256 + lane * 4) = h;
  *(ushort4*)(Zl + (size_t)wid * 256 + lane * 4) = l;
}

// ---------------- MFMA GEMM: C = [A0|A1|A2](hi+lo) @ BT(hi+lo) + bias ----------------
// wave tile 64x64 via 4x4 frags of mfma_f32_16x16x32_bf16; 3-product hi/lo split.
// No LDS: B is L2-resident (786 KB), A streamed; frag loads form 16x64B segments.
template<int WM, int WN, bool OUTF32>
__global__ __launch_bounds__(256)
void gemm_mfma_kernel(const ushort* __restrict__ A0h, const ushort* __restrict__ A0l,
                      const ushort* __restrict__ A1h, const ushort* __restrict__ A1l,
                      const ushort* __restrict__ A2h, const ushort* __restrict__ A2l,
                      const ushort* __restrict__ BTh, const ushort* __restrict__ BTl,
                      const float* __restrict__ bias,
                      float* __restrict__ Cf, ushort* __restrict__ Chi,
                      ushort* __restrict__ Clo, int M, int dn) {
  int tid = threadIdx.x;
  int w = tid >> 6, lane = tid & 63;
  int wr = w / WN, wc = w % WN;
  int m0 = blockIdx.x * (WM * 64) + wr * 64;
  int n0 = wc * 64;
  int r16 = lane & 15, kg = lane >> 4;
  const ushort* Ah[3] = {A0h, A1h, A2h};
  const ushort* Al[3] = {A0l, A1l, A2l};
  f32x4 acc[4][4] = {};
  const bf16x8 zf = {0, 0, 0, 0, 0, 0, 0, 0};

  for (int k0 = 0; k0 < 768; k0 += 32) {
    const ushort* ah = Ah[k0 >> 8];
    const ushort* al = Al[k0 >> 8];
    int kl = (k0 & 255) + kg * 8;
    bf16x8 afh[4], afl[4], bfh[4], bfl[4];
#pragma unroll
    for (int i = 0; i < 4; ++i) {
      int row = m0 + i * 16 + r16;
      if (row < M) {
        afh[i] = *(const bf16x8*)(ah + (size_t)row * 256 + kl);
        afl[i] = *(const bf16x8*)(al + (size_t)row * 256 + kl);
      } else { afh[i] = zf; afl[i] = zf; }
    }
#pragma unroll
    for (int j = 0; j < 4; ++j) {
      int n = n0 + j * 16 + r16;
      bfh[j] = *(const bf16x8*)(BTh + (size_t)n * 768 + k0 + kg * 8);
      bfl[j] = *(const bf16x8*)(BTl + (size_t)n * 768 + k0 + kg * 8);
    }
#pragma unroll
    for (int i = 0; i < 4; ++i)
#pragma unroll
      for (int j = 0; j < 4; ++j) {
        acc[i][j] = __builtin_amdgcn_mfma_f32_16x16x32_bf16(afh[i], bfh[j], acc[i][j], 0, 0, 0);
        acc[i][j] = __builtin_amdgcn_mfma_f32_16x16x32_bf16(afh[i], bfl[j], acc[i][j], 0, 0, 0);
        acc[i][j] = __builtin_amdgcn_mfma_f32_16x16x32_bf16(afl[i], bfh[j], acc[i][j], 0, 0, 0);
      }
  }
  // epilogue: C/D layout col=lane&15, row=(lane>>4)*4+reg (m89-verified)
  int qbase = (lane >> 4) * 4;
  int ccol = lane & 15;
#pragma unroll
  for (int i = 0; i < 4; ++i) {
#pragma unroll
    for (int j = 0; j < 4; ++j) {
      int col = n0 + j * 16 + ccol;
      float bv = bias[col];
#pragma unroll
      for (int q = 0; q < 4; ++q) {
        int row = m0 + i * 16 + qbase + q;
        if (row < M) {
          float c = acc[i][j][q] + bv;
          if (OUTF32) {
            Cf[(size_t)row * dn + col] = c;
          } else {
            ushort hi, lo; split2(c, hi, lo);
            Chi[(size_t)row * dn + col] = hi;
            Clo[(size_t)row * dn + col] = lo;
          }
        }
      }
    }
  }
}

// ---------------- log_softmax over rows of 64 ----------------
__global__ __launch_bounds__(256)
void logsoftmax_kernel(float* __restrict__ out, int Nn) {
  int row = blockIdx.x * 4 + (threadIdx.x >> 6);
  if (row >= Nn) return;
  int lane = threadIdx.x & 63;
  float v = out[(size_t)row * 64 + lane];
  float m = v;
  for (int off = 32; off; off >>= 1) m = fmaxf(m, __shfl_xor(m, off));
  float ex = expf(v - m);
  float s = ex;
  for (int off = 32; off; off >>= 1) s += __shfl_xor(s, off);
  out[(size_t)row * 64 + lane] = v - m - logf(s);
}

extern "C" void kernel_launch(void* const* d_in, const int* in_sizes, int n_in,
                              void* d_out, int out_size, void* d_ws, size_t ws_size,
                              hipStream_t stream) {
  const float* x   = (const float*)d_in[0];
  const int* ei1   = (const int*)d_in[1];
  const float* ew1 = (const float*)d_in[2];
  const int* ei2   = (const int*)d_in[3];
  const float* ew2 = (const float*)d_in[4];
  int Nn = in_sizes[0] / 256;
  int E  = in_sizes[1] / 2;

  const float* ibW[3][3]; const float* ibB[3][3];
  int p = 5;
  for (int b = 0; b < 3; ++b)
    for (int q = 0; q < 3; ++q) {
      ibW[b][q] = (const float*)d_in[p++];
      ibB[b][q] = (const float*)d_in[p++];
    }
  const float* lnW[3] = {(const float*)d_in[23], (const float*)d_in[25], (const float*)d_in[27]};
  const float* lnb[3] = {(const float*)d_in[24], (const float*)d_in[26], (const float*)d_in[28]};
  int dmid[3] = {256, 256, 64}, dn[3] = {256, 256, 64};

  char* ws = (char*)d_ws;
  size_t off = 0;
  auto alloc = [&](size_t bytes) {
    void* pp = ws + off;
    off = (off + bytes + 255) & ~(size_t)255;
    return pp;
  };
  size_t act = (size_t)Nn * 256 * 2;  // one bf16 activation plane
  ushort* XAh = (ushort*)alloc(act); ushort* XAl = (ushort*)alloc(act);
  ushort* XBh = (ushort*)alloc(act); ushort* XBl = (ushort*)alloc(act);
  ushort* z1h = (ushort*)alloc(act); ushort* z1l = (ushort*)alloc(act);
  ushort* z2h = (ushort*)alloc(act); ushort* z2l = (ushort*)alloc(act);
  ushort* BTh[3]; ushort* BTl[3]; float* biasf[3];
  for (int b = 0; b < 3; ++b) {
    BTh[b]   = (ushort*)alloc((size_t)768 * dn[b] * 2);
    BTl[b]   = (ushort*)alloc((size_t)768 * dn[b] * 2);
    biasf[b] = (float*)alloc((size_t)dn[b] * 4);
  }
  int* offs[2]; int* cur[2]; int2* csr[2];
  const int* eis[2] = {ei1, ei2};
  const float* ews[2] = {ew1, ew2};
  for (int g = 0; g < 2; ++g) {
    offs[g] = (int*)alloc((size_t)(Nn + 1) * 4);
    cur[g]  = (int*)alloc((size_t)Nn * 4);
    csr[g]  = (int2*)alloc((size_t)E * 8);
  }

  // weight fusion (split bf16, transposed [dn][768])
  for (int b = 0; b < 3; ++b) {
    int total = 768 * dn[b];
    fuse_w_kernel<<<(total + 255) / 256, 256, 0, stream>>>(
        ibW[b][0], ibW[b][1], ibW[b][2], lnW[b], BTh[b], BTl[b], dmid[b], dn[b]);
    fuse_b_kernel<<<dn[b], 256, 0, stream>>>(
        ibB[b][0], ibB[b][1], ibB[b][2], lnW[b], lnb[b], biasf[b], dmid[b], dn[b]);
  }

  // CSR build (per graph, reused by all 3 blocks)
  for (int g = 0; g < 2; ++g) {
    hipMemsetAsync(cur[g], 0, (size_t)Nn * 4, stream);
    hist_kernel<<<(E + 255) / 256, 256, 0, stream>>>(eis[g], cur[g], E);
    scan_kernel<<<1, 1024, 0, stream>>>(cur[g], offs[g], cur[g], Nn);
    fill_kernel<<<(E + 255) / 256, 256, 0, stream>>>(eis[g], ews[g], cur[g], csr[g], E);
  }

  // x -> bf16 hi/lo
  size_t n4 = (size_t)Nn * 64;  // float4 count
  conv_split_kernel<<<(int)((n4 + 255) / 256), 256, 0, stream>>>(x, XAh, XAl, n4);

  int aggGrid = (Nn + 3) / 4;
  int g1 = (Nn + 63) / 64;    // gemm grid, blocks 1-2 (BM=64)
  int g3 = (Nn + 255) / 256;  // gemm grid, block 3 (BM=256)

  // block 1: in XA(x) -> out XB
  agg_bf16_kernel<<<aggGrid, 256, 0, stream>>>(offs[0], csr[0], XAh, z1h, z1l, Nn);
  agg_bf16_kernel<<<aggGrid, 256, 0, stream>>>(offs[1], csr[1], XAh, z2h, z2l, Nn);
  gemm_mfma_kernel<1, 4, false><<<g1, 256, 0, stream>>>(
      XAh, XAl, z1h, z1l, z2h, z2l, BTh[0], BTl[0], biasf[0],
      nullptr, XBh, XBl, Nn, 256);

  // block 2: in XB -> out XA
  agg_bf16_kernel<<<aggGrid, 256, 0, stream>>>(offs[0], csr[0], XBh, z1h, z1l, Nn);
  agg_bf16_kernel<<<aggGrid, 256, 0, stream>>>(offs[1], csr[1], XBh, z2h, z2l, Nn);
  gemm_mfma_kernel<1, 4, false><<<g1, 256, 0, stream>>>(
      XBh, XBl, z1h, z1l, z2h, z2l, BTh[1], BTl[1], biasf[1],
      nullptr, XAh, XAl, Nn, 256);

  // block 3: in XA -> out d_out (fp32)
  agg_bf16_kernel<<<aggGrid, 256, 0, stream>>>(offs[0], csr[0], XAh, z1h, z1l, Nn);
  agg_bf16_kernel<<<aggGrid, 256, 0, stream>>>(offs[1], csr[1], XAh, z2h, z2l, Nn);
  gemm_mfma_kernel<4, 1, true><<<g3, 256, 0, stream>>>(
      XAh, XAl, z1h, z1l, z2h, z2l, BTh[2], BTl[2], biasf[2],
      (float*)d_out, nullptr, nullptr, Nn, 64);

  logsoftmax_kernel<<<aggGrid, 256, 0, stream>>>((float*)d_out, Nn);
}